// Round 24
// baseline (362.574 us; speedup 1.0000x reference)
//
#include <hip/hip_runtime.h>
#include <hip/hip_bf16.h>

typedef __hip_bfloat16 bf16;
typedef __bf16 bf16x8 __attribute__((ext_vector_type(8)));
typedef float f32x4 __attribute__((ext_vector_type(4)));

static constexpr int cB = 200, cN = 384, cM = 512, cH = 128;
static constexpr int cNN  = cB * cN;     // 76800
static constexpr int cE   = 2 * cB * cM; // 204800 edges
static constexpr int cTWOM = 2 * cM;     // 1024
static constexpr int ZROW = 2 * cM + cN; // 1408
static constexpr int CROW = cM + 2 * cN; // 1280
static constexpr int ZBASE = cB * ZROW;  // 281600

__device__ __forceinline__ float b2f(bf16 x) { return __bfloat162float(x); }
__device__ __forceinline__ bf16  f2b(float x) { return __float2bfloat16(x); }

struct bf2 { bf16 x, y; };

// ---------------- normalize edge_index / numSwitches (int32 or int64 low words) ----
__global__ __launch_bounds__(256) void k_norm_idx(const int* __restrict__ ei_raw,
                                                  const int* __restrict__ nsw_raw,
                                                  int* __restrict__ ei, int* __restrict__ nsw) {
  int z = 0;
#pragma unroll
  for (int j = 1; j < 64; j += 2) z |= ei_raw[j];
  const int f = (z == 0) ? 1 : 0;
  const int i = blockIdx.x * 256 + threadIdx.x;
  if (i < 2 * cE) ei[i] = ei_raw[i << f];
  if (blockIdx.x == 0 && threadIdx.x < cB) nsw[threadIdx.x] = nsw_raw[threadIdx.x << f];
}

// ---------------- CSR build + degree + dinv per batch ----------------
__global__ __launch_bounds__(512) void k_csr2(const int* __restrict__ ei,
                                              float* __restrict__ dinv_g,
                                              int* __restrict__ csr_off, int* __restrict__ csr_src,
                                              float* __restrict__ csr_nrm) {
  __shared__ int cnt[cN];
  __shared__ float sdinv[cN];
  __shared__ int base[cN];
  __shared__ int scanbuf[cN];
  const int tid = threadIdx.x;
  const int b = blockIdx.x;
  for (int i = tid; i < cN; i += 512) cnt[i] = 0;
  __syncthreads();
  for (int i = tid; i < cTWOM; i += 512) {
    const int d = ei[cE + b * cTWOM + i] - b * cN;
    atomicAdd(&cnt[d], 1);
  }
  __syncthreads();
  if (tid < cN) {
    const float dv = rsqrtf((float)cnt[tid] + 1.0f);   // +1 self loop
    sdinv[tid] = dv;
    dinv_g[b * cN + tid] = dv;
    scanbuf[tid] = cnt[tid];
  }
  __syncthreads();
  for (int off = 1; off < cN; off <<= 1) {
    int v = 0;
    if (tid < cN && tid >= off) v = scanbuf[tid - off];
    __syncthreads();
    if (tid < cN) scanbuf[tid] += v;
    __syncthreads();
  }
  if (tid < cN) {
    base[tid] = scanbuf[tid] - cnt[tid];
    csr_off[b * (cN + 1) + tid] = base[tid];
  }
  if (tid == 0) csr_off[b * (cN + 1) + cN] = scanbuf[cN - 1];
  if (tid < cN) cnt[tid] = 0;   // reuse as fill counters
  __syncthreads();
  for (int i = tid; i < cTWOM; i += 512) {
    const int e = b * cTWOM + i;
    const int s = ei[e];
    const int d = ei[cE + e];
    const int sl = s - b * cN;
    const int dl = d - b * cN;
    const int slot = base[dl] + atomicAdd(&cnt[dl], 1);
    csr_src[b * cTWOM + slot] = s;
    csr_nrm[b * cTWOM + slot] = sdinv[sl] * sdinv[dl];
  }
}

// ---------------- layer-1 analytic scalar gather: (a0,a1,aw) per node ----------------
__global__ __launch_bounds__(384) void k_gath3(const int* __restrict__ csr_off,
                                               const int* __restrict__ csr_src,
                                               const float* __restrict__ csr_nrm,
                                               const float* __restrict__ x,
                                               const float* __restrict__ dinv,
                                               float* __restrict__ a0_w, float* __restrict__ a1_w,
                                               float* __restrict__ aw_w) {
  __shared__ float xs[cN * 2];
  const int b = blockIdx.x, tid = threadIdx.x;
  for (int i = tid; i < cN * 2; i += 384) xs[i] = x[(size_t)b * cN * 2 + i];
  __syncthreads();
  const int nl = tid;
  const int wid = b * cN + nl;
  const int beg = csr_off[b * (cN + 1) + nl];
  const int end = csr_off[b * (cN + 1) + nl + 1];
  const int ebase = b * cTWOM;
  float a0 = 0.f, a1 = 0.f, aw = 0.f;
  for (int j = beg; j < end; ++j) {
    const int sl = csr_src[ebase + j] - b * cN;
    const float w = csr_nrm[ebase + j];
    a0 = fmaf(xs[2 * sl], w, a0);
    a1 = fmaf(xs[2 * sl + 1], w, a1);
    aw += w;
  }
  const float dn = dinv[wid];
  const float dn2 = dn * dn;
  a0 = fmaf(xs[2 * nl], dn2, a0);
  a1 = fmaf(xs[2 * nl + 1], dn2, a1);
  aw += dn2;
  a0_w[wid] = a0;
  a1_w[wid] = a1;
  aw_w[wid] = aw;
}

// ---------------- h1 = relu(a0*W1[0,h] + a1*W1[1,h] + aw*b1[h]) ----------------
__global__ __launch_bounds__(256) void k_h1a(const float* __restrict__ a0_w,
                                             const float* __restrict__ a1_w,
                                             const float* __restrict__ aw_w,
                                             const float* __restrict__ W1,
                                             const float* __restrict__ b1,
                                             bf16* __restrict__ h1) {
  const int idx = blockIdx.x * 256 + threadIdx.x;
  if (idx >= cNN * cH) return;
  const int n = idx >> 7, h = idx & 127;
  const float v = a0_w[n] * W1[h] + a1_w[n] * W1[cH + h] + aw_w[n] * b1[h];
  h1[idx] = f2b(fmaxf(v, 0.f));
}

// ---------------- gather (layer 2): hdst[n] = relu( sum_e h[src_e]*nrm_e + h[n]*dinv^2 ) ----
__global__ __launch_bounds__(256) void k_gather(const int* __restrict__ csr_off,
                                                const int* __restrict__ csr_src,
                                                const float* __restrict__ csr_nrm,
                                                const bf16* __restrict__ hsrc,
                                                const float* __restrict__ dinv,
                                                bf16* __restrict__ hdst) {
  const int wid = blockIdx.x * 4 + (threadIdx.x >> 6);   // node id in [0, cNN)
  const int lane = threadIdx.x & 63;
  const int b = wid / cN;
  const int nl = wid - b * cN;
  const int beg = csr_off[b * (cN + 1) + nl];
  const int end = csr_off[b * (cN + 1) + nl + 1];
  const int ebase = b * cTWOM;
  float a0 = 0.f, a1 = 0.f;
  for (int j = beg; j < end; ++j) {
    const int s = csr_src[ebase + j];
    const float w = csr_nrm[ebase + j];
    const unsigned u = *(const unsigned*)(hsrc + (size_t)s * cH + lane * 2);
    a0 = fmaf(__uint_as_float(u << 16), w, a0);
    a1 = fmaf(__uint_as_float(u & 0xffff0000u), w, a1);
  }
  const float dn = dinv[wid];
  const float dn2 = dn * dn;
  const unsigned us = *(const unsigned*)(hsrc + (size_t)wid * cH + lane * 2);
  a0 = fmaf(__uint_as_float(us << 16), dn2, a0);
  a1 = fmaf(__uint_as_float(us & 0xffff0000u), dn2, a1);
  bf2 pk;
  pk.x = f2b(fmaxf(a0, 0.f));
  pk.y = f2b(fmaxf(a1, 0.f));
  *(bf2*)(hdst + (size_t)wid * cH + lane * 2) = pk;
}

// ---------------- layer 2 linear via MFMA: h2raw = h1@W2 + b2 ----------------
__global__ __launch_bounds__(256) void k_lin2_mfma(const bf16* __restrict__ h1,
                                                   const bf16* __restrict__ W2t,
                                                   const float* __restrict__ b2v,
                                                   bf16* __restrict__ h2raw) {
  constexpr int FS = 136;   // row stride (272B, 16B-aligned)
  __shared__ __align__(16) bf16 feat[64 * FS];   // 17.4 KB
  __shared__ float bl[cH];
  const int tid = threadIdx.x;
  const int n0 = blockIdx.x * 64;
  const int wv = tid >> 6, ln = tid & 63;
  const int fr = ln & 15, g4 = ln >> 4, ak = g4 * 8;
  {
    const int e = tid >> 2, j = tid & 3;
    const uint4* ps = (const uint4*)(h1 + (size_t)(n0 + e) * cH);
    uint4* fp = (uint4*)(feat + e * FS);
#pragma unroll
    for (int r = 0; r < 4; ++r) fp[j * 4 + r] = ps[j * 4 + r];
  }
  for (int i = tid; i < cH; i += 256) bl[i] = b2v[i];
  bf16x8 Bf[2][4];
#pragma unroll
  for (int nt = 0; nt < 2; ++nt) {
    const bf16* bp = W2t + (size_t)(wv * 32 + nt * 16 + fr) * cH + ak;
#pragma unroll
    for (int kt = 0; kt < 4; ++kt) Bf[nt][kt] = *(const bf16x8*)(bp + kt * 32);
  }
  __syncthreads();
#pragma unroll
  for (int mt = 0; mt < 4; ++mt) {
    f32x4 acc0 = f32x4{0.f, 0.f, 0.f, 0.f};
    f32x4 acc1 = f32x4{0.f, 0.f, 0.f, 0.f};
    const bf16* ap = feat + (mt * 16 + fr) * FS + ak;
#pragma unroll
    for (int kt = 0; kt < 4; ++kt) {
      const bf16x8 a = *(const bf16x8*)(ap + kt * 32);
      acc0 = __builtin_amdgcn_mfma_f32_16x16x32_bf16(a, Bf[0][kt], acc0, 0, 0, 0);
      acc1 = __builtin_amdgcn_mfma_f32_16x16x32_bf16(a, Bf[1][kt], acc1, 0, 0, 0);
    }
#pragma unroll
    for (int j = 0; j < 2; ++j) {
      const int col = wv * 32 + j * 16 + fr;
      const f32x4 av = j ? acc1 : acc0;
#pragma unroll
      for (int i = 0; i < 4; ++i) {
        const int row = mt * 16 + g4 * 4 + i;
        h2raw[(size_t)(n0 + row) * cH + col] = f2b(av[i] + bl[col]);
      }
    }
  }
}

// ---------------- fused x_g + g_s/g_c per batch ----------------
__global__ __launch_bounds__(512) void k_xgg(const bf16* __restrict__ xg,
                                             const float* __restrict__ Ws1, const float* __restrict__ bs1,
                                             const float* __restrict__ Wc1, const float* __restrict__ bc1,
                                             float* __restrict__ g_s, float* __restrict__ g_c) {
  __shared__ float red[4][cH];
  __shared__ float xs[cH];
  const int b = blockIdx.x, tid = threadIdx.x;
  {
    const int h = tid & 127, q = tid >> 7;
    float s = 0.f;
    const bf16* p = xg + (size_t)b * cN * cH + (size_t)q * 96 * cH + h;
#pragma unroll 8
    for (int n = 0; n < 96; ++n) s += b2f(p[(size_t)n * cH]);
    red[q][h] = s;
  }
  __syncthreads();
  if (tid < cH) xs[tid] = red[0][tid] + red[1][tid] + red[2][tid] + red[3][tid];
  __syncthreads();
  {
    float acc = bs1[tid];
    for (int k = 0; k < cH; ++k) acc = fmaf(xs[k], Ws1[(2 * cH + k) * 512 + tid], acc);
    g_s[b * 512 + tid] = acc;
  }
  if (tid < 384) {
    float acc = bc1[tid];
    for (int k = 0; k < cH; ++k) acc = fmaf(xs[k], Wc1[(2 * cH + k) * 384 + tid], acc);
    g_c[b * 384 + tid] = acc;
  }
}

// ---------------- weight prep: transposes to bf16 + Wc2 pad to float4 ----------------
__global__ __launch_bounds__(256) void k_wt(const float* __restrict__ Ws1, const float* __restrict__ Wc1,
                                            const float* __restrict__ Wc2, const float* __restrict__ W2,
                                            bf16* __restrict__ Ws1t, bf16* __restrict__ Wc1t,
                                            float* __restrict__ Wc2p, bf16* __restrict__ W2t) {
  int idx = blockIdx.x * 256 + threadIdx.x;
  if (idx < 512 * 256) {
    int j = idx >> 8, k = idx & 255;
    Ws1t[idx] = f2b(Ws1[k * 512 + j]);
  }
  if (idx < 384 * 256) {
    int j = idx >> 8, k = idx & 255;
    Wc1t[idx] = f2b(Wc1[k * 384 + j]);
  }
  if (idx < 128 * 128) {
    int j = idx >> 7, k = idx & 127;
    W2t[idx] = f2b(W2[k * 128 + j]);
  }
  if (idx < 384 * 4) {
    int j = idx >> 2, o = idx & 3;
    Wc2p[idx] = (o < 3) ? Wc2[j * 3 + o] : 0.f;
  }
}

// ---------------- per-edge MLPs: 4 tiles/block, async-staged feat pipeline ----------
__global__ __launch_bounds__(256) void k_mlp_mfma(
    const int* __restrict__ ei, const int* __restrict__ nsw, const bf16* __restrict__ xg,
    const bf16* __restrict__ Ws1t, const bf16* __restrict__ Wc1t,
    const float* __restrict__ g_s, const float* __restrict__ g_c,
    const float* __restrict__ Ws2, const float* __restrict__ bs2,
    const float* __restrict__ Wc2p, const float* __restrict__ bc2,
    float* __restrict__ gt_w, float* __restrict__ wvp_w, float* __restrict__ wvc_w,
    float* __restrict__ pfc_w, float* __restrict__ out) {
  constexpr int FS = 264;   // feat row stride (bf16)
  __shared__ __align__(16) bf16 feat[64 * FS];    // 33.8 KB
  __shared__ float gsl[512];                      // 2 KB
  __shared__ float gcl[384];                      // 1.5 KB
  __shared__ float red_s[4][64][4];               // 4 KB
  __shared__ float red_c[4][64][4];               // 4 KB

  const int tid = threadIdx.x;
  const int b = blockIdx.x >> 1;
  const int tg = blockIdx.x & 1;           // tile group: 0 -> tiles 0..3, 1 -> tiles 4..7
  const int wv = tid >> 6, ln = tid & 63;
  const int fr = ln & 15;
  const int g4 = ln >> 4;
  const int swz = (fr & 7) * 8;

  const int ns = nsw[b];
  const int mb = cM - ns;                  // mb in (384, 511]; group 0 never needs S

  // staging lane mapping (4 threads per edge)
  const int se = tid >> 2, sj = tid & 3, ses = se & 7;

  // in-flight staging registers for one tile (8 x uint4)
  uint4 sp[4], sc[4];

  auto stage_load = [&](int t) {
    const int m = ((tg * 4 + t) << 6) + se;
    const int pn = ei[b * cTWOM + m];
    const int cn = ei[b * cTWOM + cM + m];
    const uint4* ps = (const uint4*)(xg + (size_t)pn * cH);
    const uint4* cs = (const uint4*)(xg + (size_t)cn * cH);
#pragma unroll
    for (int r = 0; r < 4; ++r) {
      sp[r] = ps[sj * 4 + r];
      sc[r] = cs[sj * 4 + r];
    }
  };
  auto stage_write = [&]() {
    uint4* fp = (uint4*)(feat + se * FS);
    uint4* fc = (uint4*)(feat + se * FS + 128);
#pragma unroll
    for (int r = 0; r < 4; ++r) {
      const int i = sj * 4 + r;
      fp[i ^ ses] = sp[r];
      fc[i ^ ses] = sc[r];
    }
  };

  // prologue: stage tile 0; load g vectors
  stage_load(0);
  if (tg == 1) for (int i = tid; i < 512; i += 256) gsl[i] = g_s[b * 512 + i];
  for (int i = tid; i < 384; i += 256) gcl[i] = g_c[b * 384 + i];
  stage_write();
  __syncthreads();
  stage_load(1);   // in flight during tile 0 compute

#pragma unroll 1
  for (int t = 0; t < 4; ++t) {
    const int m0 = ((tg * 4 + t) << 6);
    const bool needS = (tg == 1) && (m0 + 64 > mb);
    const bool needC = (m0 < mb);

    // ================= S path =================
    if (needS) {
      float p[4][4][4];
#pragma unroll
      for (int m = 0; m < 4; ++m)
#pragma unroll
        for (int i = 0; i < 4; ++i)
#pragma unroll
          for (int o = 0; o < 4; ++o) p[m][i][o] = 0.f;
      const bf16* bp = Ws1t + ((size_t)(wv * 128 + fr)) * 256 + g4 * 8;
#pragma unroll
      for (int c = 0; c < 2; ++c) {
        f32x4 acc[4][4];
#pragma unroll
        for (int m = 0; m < 4; ++m)
#pragma unroll
          for (int j = 0; j < 4; ++j) acc[m][j] = f32x4{0.f, 0.f, 0.f, 0.f};
        const bf16* bpc = bp + (size_t)(c * 4) * 16 * 256;
#pragma unroll
        for (int kt = 0; kt < 8; ++kt) {
          const int eo = (g4 * 8 + kt * 32) ^ swz;
          const bf16x8 a0 = *(const bf16x8*)(feat + fr * FS + eo);
          const bf16x8 a1 = *(const bf16x8*)(feat + (16 + fr) * FS + eo);
          const bf16x8 a2 = *(const bf16x8*)(feat + (32 + fr) * FS + eo);
          const bf16x8 a3 = *(const bf16x8*)(feat + (48 + fr) * FS + eo);
          const int ko = kt * 32;
#pragma unroll
          for (int j = 0; j < 4; ++j) {
            const bf16x8 bfr = *(const bf16x8*)(bpc + (size_t)j * 16 * 256 + ko);
            acc[0][j] = __builtin_amdgcn_mfma_f32_16x16x32_bf16(a0, bfr, acc[0][j], 0, 0, 0);
            acc[1][j] = __builtin_amdgcn_mfma_f32_16x16x32_bf16(a1, bfr, acc[1][j], 0, 0, 0);
            acc[2][j] = __builtin_amdgcn_mfma_f32_16x16x32_bf16(a2, bfr, acc[2][j], 0, 0, 0);
            acc[3][j] = __builtin_amdgcn_mfma_f32_16x16x32_bf16(a3, bfr, acc[3][j], 0, 0, 0);
          }
        }
#pragma unroll
        for (int j = 0; j < 4; ++j) {
          const int col = wv * 128 + (c * 4 + j) * 16 + fr;
          const float4 w4 = *(const float4*)(Ws2 + col * 4);
          const float gs = gsl[col];
#pragma unroll
          for (int m = 0; m < 4; ++m)
#pragma unroll
            for (int i = 0; i < 4; ++i) {
              const float hv = fmaxf(acc[m][j][i] + gs, 0.f);
              p[m][i][0] = fmaf(hv, w4.x, p[m][i][0]);
              p[m][i][1] = fmaf(hv, w4.y, p[m][i][1]);
              p[m][i][2] = fmaf(hv, w4.z, p[m][i][2]);
              p[m][i][3] = fmaf(hv, w4.w, p[m][i][3]);
            }
        }
      }
#pragma unroll
      for (int mask = 1; mask <= 8; mask <<= 1)
#pragma unroll
        for (int m = 0; m < 4; ++m)
#pragma unroll
          for (int i = 0; i < 4; ++i)
#pragma unroll
            for (int o = 0; o < 4; ++o) p[m][i][o] += __shfl_xor(p[m][i][o], mask);
      if (fr == 0) {
#pragma unroll
        for (int m = 0; m < 4; ++m)
#pragma unroll
          for (int i = 0; i < 4; ++i) {
            const int row = m * 16 + g4 * 4 + i;
#pragma unroll
            for (int o = 0; o < 4; ++o) red_s[wv][row][o] = p[m][i][o];
          }
      }
    }

    // ================= C path =================
    if (needC) {
      float p[4][4][4];
#pragma unroll
      for (int m = 0; m < 4; ++m)
#pragma unroll
        for (int i = 0; i < 4; ++i)
#pragma unroll
          for (int o = 0; o < 4; ++o) p[m][i][o] = 0.f;
      const bf16* bp = Wc1t + ((size_t)(wv * 96 + fr)) * 256 + g4 * 8;
#pragma unroll
      for (int c = 0; c < 2; ++c) {
        f32x4 acc[4][3];
#pragma unroll
        for (int m = 0; m < 4; ++m)
#pragma unroll
          for (int j = 0; j < 3; ++j) acc[m][j] = f32x4{0.f, 0.f, 0.f, 0.f};
        const bf16* bpc = bp + (size_t)(c * 3) * 16 * 256;
#pragma unroll
        for (int kt = 0; kt < 8; ++kt) {
          const int eo = (g4 * 8 + kt * 32) ^ swz;
          const bf16x8 a0 = *(const bf16x8*)(feat + fr * FS + eo);
          const bf16x8 a1 = *(const bf16x8*)(feat + (16 + fr) * FS + eo);
          const bf16x8 a2 = *(const bf16x8*)(feat + (32 + fr) * FS + eo);
          const bf16x8 a3 = *(const bf16x8*)(feat + (48 + fr) * FS + eo);
          const int ko = kt * 32;
#pragma unroll
          for (int j = 0; j < 3; ++j) {
            const bf16x8 bfr = *(const bf16x8*)(bpc + (size_t)j * 16 * 256 + ko);
            acc[0][j] = __builtin_amdgcn_mfma_f32_16x16x32_bf16(a0, bfr, acc[0][j], 0, 0, 0);
            acc[1][j] = __builtin_amdgcn_mfma_f32_16x16x32_bf16(a1, bfr, acc[1][j], 0, 0, 0);
            acc[2][j] = __builtin_amdgcn_mfma_f32_16x16x32_bf16(a2, bfr, acc[2][j], 0, 0, 0);
            acc[3][j] = __builtin_amdgcn_mfma_f32_16x16x32_bf16(a3, bfr, acc[3][j], 0, 0, 0);
          }
        }
#pragma unroll
        for (int j = 0; j < 3; ++j) {
          const int col = wv * 96 + (c * 3 + j) * 16 + fr;
          const float4 w4 = *(const float4*)(Wc2p + col * 4);
          const float gc = gcl[col];
#pragma unroll
          for (int m = 0; m < 4; ++m)
#pragma unroll
            for (int i = 0; i < 4; ++i) {
              const float hv = fmaxf(acc[m][j][i] + gc, 0.f);
              p[m][i][0] = fmaf(hv, w4.x, p[m][i][0]);
              p[m][i][1] = fmaf(hv, w4.y, p[m][i][1]);
              p[m][i][2] = fmaf(hv, w4.z, p[m][i][2]);
            }
        }
      }
#pragma unroll
      for (int mask = 1; mask <= 8; mask <<= 1)
#pragma unroll
        for (int m = 0; m < 4; ++m)
#pragma unroll
          for (int i = 0; i < 4; ++i)
#pragma unroll
            for (int o = 0; o < 3; ++o) p[m][i][o] += __shfl_xor(p[m][i][o], mask);
      if (fr == 0) {
#pragma unroll
        for (int m = 0; m < 4; ++m)
#pragma unroll
          for (int i = 0; i < 4; ++i) {
            const int row = m * 16 + g4 * 4 + i;
#pragma unroll
            for (int o = 0; o < 3; ++o) red_c[wv][row][o] = p[m][i][o];
          }
      }
    }
    __syncthreads();

    // ---- combine / mask / outputs for tile t ----
    if (tid < 64) {
      const int e = tid, m = m0 + e;
      const bool mk = (m >= mb);
      float gt, pf, vp, vc;
      if (mk) {
        const float s0  = red_s[0][e][0] + red_s[1][e][0] + red_s[2][e][0] + red_s[3][e][0] + bs2[0];
        gt = 1.f / (1.f + expf(-s0));
        pf = red_s[0][e][1] + red_s[1][e][1] + red_s[2][e][1] + red_s[3][e][1] + bs2[1];
        vp = red_s[0][e][2] + red_s[1][e][2] + red_s[2][e][2] + red_s[3][e][2] + bs2[2];
        vc = red_s[0][e][3] + red_s[1][e][3] + red_s[2][e][3] + red_s[3][e][3] + bs2[3];
      } else {
        gt = 1.f;
        pf = red_c[0][e][0] + red_c[1][e][0] + red_c[2][e][0] + red_c[3][e][0] + bc2[0];
        vp = red_c[0][e][1] + red_c[1][e][1] + red_c[2][e][1] + red_c[3][e][1] + bc2[1];
        vc = red_c[0][e][2] + red_c[1][e][2] + red_c[2][e][2] + red_c[3][e][2] + bc2[2];
      }
      const float pfc = pf * gt;
      const int bm = b * cM + m;
      gt_w[bm] = gt; wvp_w[bm] = vp; wvc_w[bm] = vc; pfc_w[bm] = pfc;
      out[b * ZROW + m] = pfc;
      out[b * ZROW + cM + cN + m] = gt;
    }

    if (t < 3) {
      __syncthreads();          // all waves done reading feat/red for tile t
      stage_write();            // feat <- tile t+1 (regs already landed)
      __syncthreads();          // feat ready
      if (t < 2) stage_load(t + 2);   // next-next tile in flight during t+1 compute
    }
  }
}

// ---------------- v einsums ----------------
__global__ __launch_bounds__(256) void k_v(const float* __restrict__ incP, const float* __restrict__ incC,
                                           const float* __restrict__ wvp, const float* __restrict__ wvc,
                                           const float* __restrict__ invdeg, float* __restrict__ v_w,
                                           float* __restrict__ out) {
  const int wid = blockIdx.x * 4 + (threadIdx.x >> 6);
  const int lane = threadIdx.x & 63;
  const int b = wid / cN, n = wid % cN;
  const size_t rowoff = (size_t)(b * cN + n) * cM + lane * 8;
  const float4 p0 = *(const float4*)(incP + rowoff);
  const float4 p1 = *(const float4*)(incP + rowoff + 4);
  const float4 c0 = *(const float4*)(incC + rowoff);
  const float4 c1 = *(const float4*)(incC + rowoff + 4);
  const float* wp = wvp + b * cM + lane * 8;
  const float* wc = wvc + b * cM + lane * 8;
  float s;
  s = p0.x * wp[0] + p0.y * wp[1] + p0.z * wp[2] + p0.w * wp[3] +
      p1.x * wp[4] + p1.y * wp[5] + p1.z * wp[6] + p1.w * wp[7];
  s += c0.x * wc[0] + c0.y * wc[1] + c0.z * wc[2] + c0.w * wc[3] +
       c1.x * wc[4] + c1.y * wc[5] + c1.z * wc[6] + c1.w * wc[7];
#pragma unroll
  for (int off = 32; off >= 1; off >>= 1) s += __shfl_down(s, off);
  if (lane == 0) {
    float val = invdeg[b * cN + n] * s;
    if (n == 0) val = 1.0f;
    v_w[b * cN + n] = val;
    out[b * ZROW + cM + n] = val;
  }
}

// ---------------- q_fc = (A^T v) * graph_topo ----------------
__global__ __launch_bounds__(256) void k_qfc(const float* __restrict__ A, const float* __restrict__ v_w,
                                             const float* __restrict__ gt_w, float* __restrict__ qfc_w,
                                             float* __restrict__ out) {
  __shared__ float vs[cN];
  const int b = blockIdx.x >> 1;
  const int m = ((blockIdx.x & 1) << 8) + threadIdx.x;
  for (int i = threadIdx.x; i < cN; i += 256) vs[i] = v_w[b * cN + i];
  __syncthreads();
  float s = 0.f;
  for (int n = 0; n < cN; ++n) s = fmaf(A[n * cM + m], vs[n], s);
  const int bm = b * cM + m;
  const float q = s * gt_w[bm];
  qfc_w[bm] = q;
  out[ZBASE + b * CROW + m] = q;
}

// ---------------- pg / qg: one wave per (b,n); coalesced A-row reads ----------------
__global__ __launch_bounds__(256) void k_pgqg(const float* __restrict__ A, const float* __restrict__ x,
                                              const float* __restrict__ pfc, const float* __restrict__ qfc,
                                              float* __restrict__ out) {
  const int wid = blockIdx.x * 4 + (threadIdx.x >> 6);
  const int lane = threadIdx.x & 63;
  const int b = wid / cN, n = wid - b * cN;
  const float* ar = A + (size_t)n * cM + lane * 8;
  const float* pf = pfc + b * cM + lane * 8;
  const float* qf = qfc + b * cM + lane * 8;
  const float4 a0 = *(const float4*)(ar);
  const float4 a1 = *(const float4*)(ar + 4);
  float ps, qs;
  ps = a0.x * pf[0] + a0.y * pf[1] + a0.z * pf[2] + a0.w * pf[3] +
       a1.x * pf[4] + a1.y * pf[5] + a1.z * pf[6] + a1.w * pf[7];
  qs = a0.x * qf[0] + a0.y * qf[1] + a0.z * qf[2] + a0.w * qf[3] +
       a1.x * qf[4] + a1.y * qf[5] + a1.z * qf[6] + a1.w * qf[7];
#pragma unroll
  for (int off = 32; off >= 1; off >>= 1) {
    ps += __shfl_down(ps, off);
    qs += __shfl_down(qs, off);
  }
  if (lane == 0) {
    out[ZBASE + b * CROW + cM + n] = x[2 * (size_t)wid] + ps;
    out[ZBASE + b * CROW + cM + cN + n] = x[2 * (size_t)wid + 1] + qs;
  }
}

extern "C" void kernel_launch(void* const* d_in, const int* in_sizes, int n_in,
                              void* d_out, int out_size, void* d_ws, size_t ws_size,
                              hipStream_t stream) {
  const bool dict_order = (in_sizes[1] == 2 * cE);
  int IEI, INSW, IIVD, IIP, IIC, IA, IW;
  if (dict_order) { IEI = 1; INSW = 2; IIVD = 3; IIP = 4; IIC = 5; IA = 6; IW = 7; }
  else            { IIVD = 1; IIP = 2; IIC = 3; IA = 4; IW = 5; IEI = 17; INSW = 18; }

  const float* x = (const float*)d_in[0];
  const int* ei_raw = (const int*)d_in[IEI];
  const int* nsw_raw = (const int*)d_in[INSW];
  const float* invdeg = (const float*)d_in[IIVD];
  const float* incP = (const float*)d_in[IIP];
  const float* incC = (const float*)d_in[IIC];
  const float* A = (const float*)d_in[IA];
  const float* W1 = (const float*)d_in[IW + 0];
  const float* b1 = (const float*)d_in[IW + 1];
  const float* W2 = (const float*)d_in[IW + 2];
  const float* b2 = (const float*)d_in[IW + 3];
  const float* Ws1 = (const float*)d_in[IW + 4];
  const float* bs1 = (const float*)d_in[IW + 5];
  const float* Ws2 = (const float*)d_in[IW + 6];
  const float* bs2 = (const float*)d_in[IW + 7];
  const float* Wc1 = (const float*)d_in[IW + 8];
  const float* bc1 = (const float*)d_in[IW + 9];
  const float* Wc2 = (const float*)d_in[IW + 10];
  const float* bc2 = (const float*)d_in[IW + 11];
  float* out = (float*)d_out;

  // ---- workspace (~48 MB; well under proven 83.6 MB) ----
  char* w = (char*)d_ws;
  auto alloc = [&](size_t bytes) { void* p = (void*)w; w += (bytes + 255) & ~(size_t)255; return p; };
  float* dinv = (float*)alloc((size_t)cNN * 4);
  int* ei = (int*)alloc((size_t)2 * cE * 4);
  int* nsw = (int*)alloc((size_t)cB * 4);
  bf16* hbufA = (bf16*)alloc((size_t)cNN * cH * 2);  // h2raw
  bf16* hbufB = (bf16*)alloc((size_t)cNN * cH * 2);  // h1 -> xg
  int* csr_off = (int*)alloc((size_t)cB * (cN + 1) * 4);
  int* csr_src = (int*)alloc((size_t)cE * 4);
  float* csr_nrm = (float*)alloc((size_t)cE * 4);
  float* a0_w = (float*)alloc((size_t)cNN * 4);
  float* a1_w = (float*)alloc((size_t)cNN * 4);
  float* aw_w = (float*)alloc((size_t)cNN * 4);
  bf16* Ws1t = (bf16*)alloc((size_t)512 * 256 * 2);
  bf16* Wc1t = (bf16*)alloc((size_t)384 * 256 * 2);
  bf16* W2t = (bf16*)alloc((size_t)128 * 128 * 2);
  float* g_s = (float*)alloc((size_t)cB * 512 * 4);
  float* g_c = (float*)alloc((size_t)cB * 384 * 4);
  float* Wc2p = (float*)alloc((size_t)384 * 4 * 4);
  float* gt_w = (float*)alloc((size_t)cB * cM * 4);
  float* wvp_w = (float*)alloc((size_t)cB * cM * 4);
  float* wvc_w = (float*)alloc((size_t)cB * cM * 4);
  float* pfc_w = (float*)alloc((size_t)cB * cM * 4);
  float* qfc_w = (float*)alloc((size_t)cB * cM * 4);
  float* v_w = (float*)alloc((size_t)cB * cN * 4);

  const int NH = cNN * cH;
  k_norm_idx<<<(2 * cE) / 256, 256, 0, stream>>>(ei_raw, nsw_raw, ei, nsw);
  k_csr2<<<cB, 512, 0, stream>>>(ei, dinv, csr_off, csr_src, csr_nrm);

  // GCN layer 1 (analytic rank-3): 3-scalar gather + elementwise expansion -> h1 in hbufB
  k_gath3<<<cB, 384, 0, stream>>>(csr_off, csr_src, csr_nrm, x, dinv, a0_w, a1_w, aw_w);
  k_h1a<<<NH / 256, 256, 0, stream>>>(a0_w, a1_w, aw_w, W1, b1, hbufB);

  // weight prep (no deps on h)
  k_wt<<<512, 256, 0, stream>>>(Ws1, Wc1, Wc2, W2, Ws1t, Wc1t, Wc2p, W2t);

  // GCN layer 2: lin2 B -> A (h2raw) on MFMA; gather A -> B (xg)
  k_lin2_mfma<<<cNN / 64, 256, 0, stream>>>(hbufB, W2t, b2, hbufA);
  k_gather<<<cNN / 4, 256, 0, stream>>>(csr_off, csr_src, csr_nrm, hbufA, dinv, hbufB);

  bf16* xg = hbufB;
  k_xgg<<<cB, 512, 0, stream>>>(xg, Ws1, bs1, Wc1, bc1, g_s, g_c);

  // per-edge MLPs: 4-tile pipelined blocks (async feat staging)
  k_mlp_mfma<<<cB * 2, 256, 0, stream>>>(ei, nsw, xg, Ws1t, Wc1t, g_s, g_c,
                                         Ws2, bs2, Wc2p, bc2,
                                         gt_w, wvp_w, wvc_w, pfc_w, out);

  k_v<<<cB * cN / 4, 256, 0, stream>>>(incP, incC, wvp_w, wvc_w, invdeg, v_w, out);
  k_qfc<<<cB * cM / 256, 256, 0, stream>>>(A, v_w, gt_w, qfc_w, out);
  k_pgqg<<<cNN / 4, 256, 0, stream>>>(A, x, pfc_w, qfc_w, out);
}

// Round 25
// 277.558 us; speedup vs baseline: 1.3063x; 1.3063x over previous
//
#include <hip/hip_runtime.h>
#include <hip/hip_bf16.h>

typedef __hip_bfloat16 bf16;
typedef __bf16 bf16x8 __attribute__((ext_vector_type(8)));
typedef float f32x4 __attribute__((ext_vector_type(4)));

static constexpr int cB = 200, cN = 384, cM = 512, cH = 128;
static constexpr int cNN  = cB * cN;     // 76800
static constexpr int cE   = 2 * cB * cM; // 204800 edges
static constexpr int cTWOM = 2 * cM;     // 1024
static constexpr int ZROW = 2 * cM + cN; // 1408
static constexpr int CROW = cM + 2 * cN; // 1280
static constexpr int ZBASE = cB * ZROW;  // 281600

__device__ __forceinline__ float b2f(bf16 x) { return __bfloat162float(x); }
__device__ __forceinline__ bf16  f2b(float x) { return __float2bfloat16(x); }

struct bf2 { bf16 x, y; };

// ---------------- normalize edge_index / numSwitches (int32 or int64 low words) ----
__global__ __launch_bounds__(256) void k_norm_idx(const int* __restrict__ ei_raw,
                                                  const int* __restrict__ nsw_raw,
                                                  int* __restrict__ ei, int* __restrict__ nsw) {
  int z = 0;
#pragma unroll
  for (int j = 1; j < 64; j += 2) z |= ei_raw[j];
  const int f = (z == 0) ? 1 : 0;
  const int i = blockIdx.x * 256 + threadIdx.x;
  if (i < 2 * cE) ei[i] = ei_raw[i << f];
  if (blockIdx.x == 0 && threadIdx.x < cB) nsw[threadIdx.x] = nsw_raw[threadIdx.x << f];
}

// ---------------- CSR build + degree + dinv per batch ----------------
__global__ __launch_bounds__(512) void k_csr2(const int* __restrict__ ei,
                                              float* __restrict__ dinv_g,
                                              int* __restrict__ csr_off, int* __restrict__ csr_src,
                                              float* __restrict__ csr_nrm) {
  __shared__ int cnt[cN];
  __shared__ float sdinv[cN];
  __shared__ int base[cN];
  __shared__ int scanbuf[cN];
  const int tid = threadIdx.x;
  const int b = blockIdx.x;
  for (int i = tid; i < cN; i += 512) cnt[i] = 0;
  __syncthreads();
  for (int i = tid; i < cTWOM; i += 512) {
    const int d = ei[cE + b * cTWOM + i] - b * cN;
    atomicAdd(&cnt[d], 1);
  }
  __syncthreads();
  if (tid < cN) {
    const float dv = rsqrtf((float)cnt[tid] + 1.0f);   // +1 self loop
    sdinv[tid] = dv;
    dinv_g[b * cN + tid] = dv;
    scanbuf[tid] = cnt[tid];
  }
  __syncthreads();
  for (int off = 1; off < cN; off <<= 1) {
    int v = 0;
    if (tid < cN && tid >= off) v = scanbuf[tid - off];
    __syncthreads();
    if (tid < cN) scanbuf[tid] += v;
    __syncthreads();
  }
  if (tid < cN) {
    base[tid] = scanbuf[tid] - cnt[tid];
    csr_off[b * (cN + 1) + tid] = base[tid];
  }
  if (tid == 0) csr_off[b * (cN + 1) + cN] = scanbuf[cN - 1];
  if (tid < cN) cnt[tid] = 0;   // reuse as fill counters
  __syncthreads();
  for (int i = tid; i < cTWOM; i += 512) {
    const int e = b * cTWOM + i;
    const int s = ei[e];
    const int d = ei[cE + e];
    const int sl = s - b * cN;
    const int dl = d - b * cN;
    const int slot = base[dl] + atomicAdd(&cnt[dl], 1);
    csr_src[b * cTWOM + slot] = s;
    csr_nrm[b * cTWOM + slot] = sdinv[sl] * sdinv[dl];
  }
}

// ---------------- layer-1 analytic scalar gather: (a0,a1,aw) per node ----------------
__global__ __launch_bounds__(384) void k_gath3(const int* __restrict__ csr_off,
                                               const int* __restrict__ csr_src,
                                               const float* __restrict__ csr_nrm,
                                               const float* __restrict__ x,
                                               const float* __restrict__ dinv,
                                               float* __restrict__ a0_w, float* __restrict__ a1_w,
                                               float* __restrict__ aw_w) {
  __shared__ float xs[cN * 2];
  const int b = blockIdx.x, tid = threadIdx.x;
  for (int i = tid; i < cN * 2; i += 384) xs[i] = x[(size_t)b * cN * 2 + i];
  __syncthreads();
  const int nl = tid;
  const int wid = b * cN + nl;
  const int beg = csr_off[b * (cN + 1) + nl];
  const int end = csr_off[b * (cN + 1) + nl + 1];
  const int ebase = b * cTWOM;
  float a0 = 0.f, a1 = 0.f, aw = 0.f;
  for (int j = beg; j < end; ++j) {
    const int sl = csr_src[ebase + j] - b * cN;
    const float w = csr_nrm[ebase + j];
    a0 = fmaf(xs[2 * sl], w, a0);
    a1 = fmaf(xs[2 * sl + 1], w, a1);
    aw += w;
  }
  const float dn = dinv[wid];
  const float dn2 = dn * dn;
  a0 = fmaf(xs[2 * nl], dn2, a0);
  a1 = fmaf(xs[2 * nl + 1], dn2, a1);
  aw += dn2;
  a0_w[wid] = a0;
  a1_w[wid] = a1;
  aw_w[wid] = aw;
}

// ---------------- h1 = relu(a0*W1[0,h] + a1*W1[1,h] + aw*b1[h]) ----------------
__global__ __launch_bounds__(256) void k_h1a(const float* __restrict__ a0_w,
                                             const float* __restrict__ a1_w,
                                             const float* __restrict__ aw_w,
                                             const float* __restrict__ W1,
                                             const float* __restrict__ b1,
                                             bf16* __restrict__ h1) {
  const int idx = blockIdx.x * 256 + threadIdx.x;
  if (idx >= cNN * cH) return;
  const int n = idx >> 7, h = idx & 127;
  const float v = a0_w[n] * W1[h] + a1_w[n] * W1[cH + h] + aw_w[n] * b1[h];
  h1[idx] = f2b(fmaxf(v, 0.f));
}

// ---------------- gather (layer 2), XCD-localized: blocks of one batch -> one XCD ----
__global__ __launch_bounds__(256) void k_gather(const int* __restrict__ csr_off,
                                                const int* __restrict__ csr_src,
                                                const float* __restrict__ csr_nrm,
                                                const bf16* __restrict__ hsrc,
                                                const float* __restrict__ dinv,
                                                bf16* __restrict__ hdst) {
  // swizzle: b = blk % 200 (200 % 8 == 0 => all 96 blocks of a batch share an XCD)
  const int bb = blockIdx.x % cB;
  const int grp = blockIdx.x / cB;
  const int wid = bb * cN + grp * 4 + (threadIdx.x >> 6);
  const int lane = threadIdx.x & 63;
  const int b = bb;
  const int nl = wid - b * cN;
  const int beg = csr_off[b * (cN + 1) + nl];
  const int end = csr_off[b * (cN + 1) + nl + 1];
  const int ebase = b * cTWOM;
  float a0 = 0.f, a1 = 0.f;
  for (int j = beg; j < end; ++j) {
    const int s = csr_src[ebase + j];
    const float w = csr_nrm[ebase + j];
    const unsigned u = *(const unsigned*)(hsrc + (size_t)s * cH + lane * 2);
    a0 = fmaf(__uint_as_float(u << 16), w, a0);
    a1 = fmaf(__uint_as_float(u & 0xffff0000u), w, a1);
  }
  const float dn = dinv[wid];
  const float dn2 = dn * dn;
  const unsigned us = *(const unsigned*)(hsrc + (size_t)wid * cH + lane * 2);
  a0 = fmaf(__uint_as_float(us << 16), dn2, a0);
  a1 = fmaf(__uint_as_float(us & 0xffff0000u), dn2, a1);
  bf2 pk;
  pk.x = f2b(fmaxf(a0, 0.f));
  pk.y = f2b(fmaxf(a1, 0.f));
  *(bf2*)(hdst + (size_t)wid * cH + lane * 2) = pk;
}

// ---------------- layer 2 linear via MFMA: h2raw = h1@W2 + b2 ----------------
__global__ __launch_bounds__(256) void k_lin2_mfma(const bf16* __restrict__ h1,
                                                   const bf16* __restrict__ W2t,
                                                   const float* __restrict__ b2v,
                                                   bf16* __restrict__ h2raw) {
  constexpr int FS = 136;   // row stride (272B, 16B-aligned)
  __shared__ __align__(16) bf16 feat[64 * FS];   // 17.4 KB
  __shared__ float bl[cH];
  const int tid = threadIdx.x;
  const int n0 = blockIdx.x * 64;
  const int wv = tid >> 6, ln = tid & 63;
  const int fr = ln & 15, g4 = ln >> 4, ak = g4 * 8;
  {
    const int e = tid >> 2, j = tid & 3;
    const uint4* ps = (const uint4*)(h1 + (size_t)(n0 + e) * cH);
    uint4* fp = (uint4*)(feat + e * FS);
#pragma unroll
    for (int r = 0; r < 4; ++r) fp[j * 4 + r] = ps[j * 4 + r];
  }
  for (int i = tid; i < cH; i += 256) bl[i] = b2v[i];
  bf16x8 Bf[2][4];
#pragma unroll
  for (int nt = 0; nt < 2; ++nt) {
    const bf16* bp = W2t + (size_t)(wv * 32 + nt * 16 + fr) * cH + ak;
#pragma unroll
    for (int kt = 0; kt < 4; ++kt) Bf[nt][kt] = *(const bf16x8*)(bp + kt * 32);
  }
  __syncthreads();
#pragma unroll
  for (int mt = 0; mt < 4; ++mt) {
    f32x4 acc0 = f32x4{0.f, 0.f, 0.f, 0.f};
    f32x4 acc1 = f32x4{0.f, 0.f, 0.f, 0.f};
    const bf16* ap = feat + (mt * 16 + fr) * FS + ak;
#pragma unroll
    for (int kt = 0; kt < 4; ++kt) {
      const bf16x8 a = *(const bf16x8*)(ap + kt * 32);
      acc0 = __builtin_amdgcn_mfma_f32_16x16x32_bf16(a, Bf[0][kt], acc0, 0, 0, 0);
      acc1 = __builtin_amdgcn_mfma_f32_16x16x32_bf16(a, Bf[1][kt], acc1, 0, 0, 0);
    }
#pragma unroll
    for (int j = 0; j < 2; ++j) {
      const int col = wv * 32 + j * 16 + fr;
      const f32x4 av = j ? acc1 : acc0;
#pragma unroll
      for (int i = 0; i < 4; ++i) {
        const int row = mt * 16 + g4 * 4 + i;
        h2raw[(size_t)(n0 + row) * cH + col] = f2b(av[i] + bl[col]);
      }
    }
  }
}

// ---------------- fused x_g + g_s/g_c per batch ----------------
__global__ __launch_bounds__(512) void k_xgg(const bf16* __restrict__ xg,
                                             const float* __restrict__ Ws1, const float* __restrict__ bs1,
                                             const float* __restrict__ Wc1, const float* __restrict__ bc1,
                                             float* __restrict__ g_s, float* __restrict__ g_c) {
  __shared__ float red[4][cH];
  __shared__ float xs[cH];
  const int b = blockIdx.x, tid = threadIdx.x;
  {
    const int h = tid & 127, q = tid >> 7;
    float s = 0.f;
    const bf16* p = xg + (size_t)b * cN * cH + (size_t)q * 96 * cH + h;
#pragma unroll 8
    for (int n = 0; n < 96; ++n) s += b2f(p[(size_t)n * cH]);
    red[q][h] = s;
  }
  __syncthreads();
  if (tid < cH) xs[tid] = red[0][tid] + red[1][tid] + red[2][tid] + red[3][tid];
  __syncthreads();
  {
    float acc = bs1[tid];
    for (int k = 0; k < cH; ++k) acc = fmaf(xs[k], Ws1[(2 * cH + k) * 512 + tid], acc);
    g_s[b * 512 + tid] = acc;
  }
  if (tid < 384) {
    float acc = bc1[tid];
    for (int k = 0; k < cH; ++k) acc = fmaf(xs[k], Wc1[(2 * cH + k) * 384 + tid], acc);
    g_c[b * 384 + tid] = acc;
  }
}

// ---------------- weight prep: transposes to bf16 + Wc2 pad to float4 ----------------
__global__ __launch_bounds__(256) void k_wt(const float* __restrict__ Ws1, const float* __restrict__ Wc1,
                                            const float* __restrict__ Wc2, const float* __restrict__ W2,
                                            bf16* __restrict__ Ws1t, bf16* __restrict__ Wc1t,
                                            float* __restrict__ Wc2p, bf16* __restrict__ W2t) {
  int idx = blockIdx.x * 256 + threadIdx.x;
  if (idx < 512 * 256) {
    int j = idx >> 8, k = idx & 255;
    Ws1t[idx] = f2b(Ws1[k * 512 + j]);
  }
  if (idx < 384 * 256) {
    int j = idx >> 8, k = idx & 255;
    Wc1t[idx] = f2b(Wc1[k * 384 + j]);
  }
  if (idx < 128 * 128) {
    int j = idx >> 7, k = idx & 127;
    W2t[idx] = f2b(W2[k * 128 + j]);
  }
  if (idx < 384 * 4) {
    int j = idx >> 2, o = idx & 3;
    Wc2p[idx] = (o < 3) ? Wc2[j * 3 + o] : 0.f;
  }
}

// ---------------- per-edge MLPs via MFMA: 64 edges/block, mask-skip + XCD locality ----
__global__ __launch_bounds__(256) void k_mlp_mfma(
    const int* __restrict__ ei, const int* __restrict__ nsw, const bf16* __restrict__ xg,
    const bf16* __restrict__ Ws1t, const bf16* __restrict__ Wc1t,
    const float* __restrict__ g_s, const float* __restrict__ g_c,
    const float* __restrict__ Ws2, const float* __restrict__ bs2,
    const float* __restrict__ Wc2p, const float* __restrict__ bc2,
    float* __restrict__ gt_w, float* __restrict__ wvp_w, float* __restrict__ wvc_w,
    float* __restrict__ pfc_w, float* __restrict__ out) {
  constexpr int FS = 264;   // feat row stride (bf16)
  __shared__ __align__(16) bf16 feat[64 * FS];    // 33.8 KB
  __shared__ float gsl[512];                      // 2 KB
  __shared__ float gcl[384];                      // 1.5 KB
  __shared__ float red_s[4][64][4];               // 4 KB
  __shared__ float red_c[4][64][4];               // 4 KB

  const int tid = threadIdx.x;
  // swizzle: b = blk % 200 => all 8 tiles of a batch share an XCD (200 % 8 == 0)
  const int b = blockIdx.x % cB;
  const int m0 = (blockIdx.x / cB) << 6;   // 64 edges per block
  const int wv = tid >> 6, ln = tid & 63;
  const int fr = ln & 15;
  const int g4 = ln >> 4;            // 0..3
  const int swz = (fr & 7) * 8;      // element XOR for A reads

  // mask boundary: S outputs used only for m >= mb; C only for m < mb (block-uniform)
  const int ns = nsw[b];
  const int mb = cM - ns;
  const bool needS = (m0 + 64 > mb);
  const bool needC = (m0 < mb);

  // ---- gather feat[e][0:256] = [xg[pn] | xg[cn]], XOR-swizzled rows ----
  {
    const int e = tid >> 2, j = tid & 3;     // 4 threads per edge, 4 uint4 per half each
    const int m = m0 + e;
    const int pn = ei[b * cTWOM + m];
    const int cn = ei[b * cTWOM + cM + m];
    const int es = e & 7;                    // uint4-index XOR
    const uint4* ps = (const uint4*)(xg + (size_t)pn * cH);
    const uint4* cs = (const uint4*)(xg + (size_t)cn * cH);
    uint4* fp = (uint4*)(feat + e * FS);
    uint4* fc = (uint4*)(feat + e * FS + 128);
#pragma unroll
    for (int r = 0; r < 4; ++r) {
      const int i = j * 4 + r;
      fp[i ^ es] = ps[i];
      fc[i ^ es] = cs[i];
    }
  }
  if (needS) for (int i = tid; i < 512; i += 256) gsl[i] = g_s[b * 512 + i];
  if (needC) for (int i = tid; i < 384; i += 256) gcl[i] = g_c[b * 384 + i];
  __syncthreads();

  // ================= S path (only if some edge in tile is masked) =================
  if (needS) {
    float p[4][4][4];   // [m][i][o]
#pragma unroll
    for (int m = 0; m < 4; ++m)
#pragma unroll
      for (int i = 0; i < 4; ++i)
#pragma unroll
        for (int o = 0; o < 4; ++o) p[m][i][o] = 0.f;
    const bf16* bp = Ws1t + ((size_t)(wv * 128 + fr)) * 256 + g4 * 8;
#pragma unroll
    for (int c = 0; c < 2; ++c) {
      f32x4 acc[4][4];
#pragma unroll
      for (int m = 0; m < 4; ++m)
#pragma unroll
        for (int j = 0; j < 4; ++j) acc[m][j] = f32x4{0.f, 0.f, 0.f, 0.f};
      const bf16* bpc = bp + (size_t)(c * 4) * 16 * 256;
#pragma unroll
      for (int kt = 0; kt < 8; ++kt) {
        const int eo = (g4 * 8 + kt * 32) ^ swz;   // swizzled element offset
        const bf16x8 a0 = *(const bf16x8*)(feat + fr * FS + eo);
        const bf16x8 a1 = *(const bf16x8*)(feat + (16 + fr) * FS + eo);
        const bf16x8 a2 = *(const bf16x8*)(feat + (32 + fr) * FS + eo);
        const bf16x8 a3 = *(const bf16x8*)(feat + (48 + fr) * FS + eo);
        const int ko = kt * 32;
#pragma unroll
        for (int j = 0; j < 4; ++j) {
          const bf16x8 bfr = *(const bf16x8*)(bpc + (size_t)j * 16 * 256 + ko);
          acc[0][j] = __builtin_amdgcn_mfma_f32_16x16x32_bf16(a0, bfr, acc[0][j], 0, 0, 0);
          acc[1][j] = __builtin_amdgcn_mfma_f32_16x16x32_bf16(a1, bfr, acc[1][j], 0, 0, 0);
          acc[2][j] = __builtin_amdgcn_mfma_f32_16x16x32_bf16(a2, bfr, acc[2][j], 0, 0, 0);
          acc[3][j] = __builtin_amdgcn_mfma_f32_16x16x32_bf16(a3, bfr, acc[3][j], 0, 0, 0);
        }
      }
#pragma unroll
      for (int j = 0; j < 4; ++j) {
        const int col = wv * 128 + (c * 4 + j) * 16 + fr;
        const float4 w4 = *(const float4*)(Ws2 + col * 4);
        const float gs = gsl[col];
#pragma unroll
        for (int m = 0; m < 4; ++m)
#pragma unroll
          for (int i = 0; i < 4; ++i) {
            const float hv = fmaxf(acc[m][j][i] + gs, 0.f);
            p[m][i][0] = fmaf(hv, w4.x, p[m][i][0]);
            p[m][i][1] = fmaf(hv, w4.y, p[m][i][1]);
            p[m][i][2] = fmaf(hv, w4.z, p[m][i][2]);
            p[m][i][3] = fmaf(hv, w4.w, p[m][i][3]);
          }
      }
    }
#pragma unroll
    for (int mask = 1; mask <= 8; mask <<= 1)
#pragma unroll
      for (int m = 0; m < 4; ++m)
#pragma unroll
        for (int i = 0; i < 4; ++i)
#pragma unroll
          for (int o = 0; o < 4; ++o) p[m][i][o] += __shfl_xor(p[m][i][o], mask);
    if (fr == 0) {
#pragma unroll
      for (int m = 0; m < 4; ++m)
#pragma unroll
        for (int i = 0; i < 4; ++i) {
          const int row = m * 16 + g4 * 4 + i;
#pragma unroll
          for (int o = 0; o < 4; ++o) red_s[wv][row][o] = p[m][i][o];
        }
    }
  }

  // ================= C path (only if some edge in tile is unmasked) ============
  if (needC) {
    float p[4][4][4];
#pragma unroll
    for (int m = 0; m < 4; ++m)
#pragma unroll
      for (int i = 0; i < 4; ++i)
#pragma unroll
        for (int o = 0; o < 4; ++o) p[m][i][o] = 0.f;
    const bf16* bp = Wc1t + ((size_t)(wv * 96 + fr)) * 256 + g4 * 8;
#pragma unroll
    for (int c = 0; c < 2; ++c) {
      f32x4 acc[4][3];
#pragma unroll
      for (int m = 0; m < 4; ++m)
#pragma unroll
        for (int j = 0; j < 3; ++j) acc[m][j] = f32x4{0.f, 0.f, 0.f, 0.f};
      const bf16* bpc = bp + (size_t)(c * 3) * 16 * 256;
#pragma unroll
      for (int kt = 0; kt < 8; ++kt) {
        const int eo = (g4 * 8 + kt * 32) ^ swz;
        const bf16x8 a0 = *(const bf16x8*)(feat + fr * FS + eo);
        const bf16x8 a1 = *(const bf16x8*)(feat + (16 + fr) * FS + eo);
        const bf16x8 a2 = *(const bf16x8*)(feat + (32 + fr) * FS + eo);
        const bf16x8 a3 = *(const bf16x8*)(feat + (48 + fr) * FS + eo);
        const int ko = kt * 32;
#pragma unroll
        for (int j = 0; j < 3; ++j) {
          const bf16x8 bfr = *(const bf16x8*)(bpc + (size_t)j * 16 * 256 + ko);
          acc[0][j] = __builtin_amdgcn_mfma_f32_16x16x32_bf16(a0, bfr, acc[0][j], 0, 0, 0);
          acc[1][j] = __builtin_amdgcn_mfma_f32_16x16x32_bf16(a1, bfr, acc[1][j], 0, 0, 0);
          acc[2][j] = __builtin_amdgcn_mfma_f32_16x16x32_bf16(a2, bfr, acc[2][j], 0, 0, 0);
          acc[3][j] = __builtin_amdgcn_mfma_f32_16x16x32_bf16(a3, bfr, acc[3][j], 0, 0, 0);
        }
      }
#pragma unroll
      for (int j = 0; j < 3; ++j) {
        const int col = wv * 96 + (c * 3 + j) * 16 + fr;
        const float4 w4 = *(const float4*)(Wc2p + col * 4);
        const float gc = gcl[col];
#pragma unroll
        for (int m = 0; m < 4; ++m)
#pragma unroll
          for (int i = 0; i < 4; ++i) {
            const float hv = fmaxf(acc[m][j][i] + gc, 0.f);
            p[m][i][0] = fmaf(hv, w4.x, p[m][i][0]);
            p[m][i][1] = fmaf(hv, w4.y, p[m][i][1]);
            p[m][i][2] = fmaf(hv, w4.z, p[m][i][2]);
          }
      }
    }
#pragma unroll
    for (int mask = 1; mask <= 8; mask <<= 1)
#pragma unroll
      for (int m = 0; m < 4; ++m)
#pragma unroll
        for (int i = 0; i < 4; ++i)
#pragma unroll
          for (int o = 0; o < 3; ++o) p[m][i][o] += __shfl_xor(p[m][i][o], mask);
    if (fr == 0) {
#pragma unroll
      for (int m = 0; m < 4; ++m)
#pragma unroll
        for (int i = 0; i < 4; ++i) {
          const int row = m * 16 + g4 * 4 + i;
#pragma unroll
          for (int o = 0; o < 3; ++o) red_c[wv][row][o] = p[m][i][o];
        }
    }
  }
  __syncthreads();

  // ---- combine / mask / outputs (reads only the computed path per edge) ----
  if (tid < 64) {
    const int e = tid, m = m0 + e;
    const bool mk = (m >= mb);
    float gt, pf, vp, vc;
    if (mk) {   // mk==true implies needS
      const float s0  = red_s[0][e][0] + red_s[1][e][0] + red_s[2][e][0] + red_s[3][e][0] + bs2[0];
      gt = 1.f / (1.f + expf(-s0));
      pf = red_s[0][e][1] + red_s[1][e][1] + red_s[2][e][1] + red_s[3][e][1] + bs2[1];
      vp = red_s[0][e][2] + red_s[1][e][2] + red_s[2][e][2] + red_s[3][e][2] + bs2[2];
      vc = red_s[0][e][3] + red_s[1][e][3] + red_s[2][e][3] + red_s[3][e][3] + bs2[3];
    } else {    // !mk implies needC
      gt = 1.f;
      pf = red_c[0][e][0] + red_c[1][e][0] + red_c[2][e][0] + red_c[3][e][0] + bc2[0];
      vp = red_c[0][e][1] + red_c[1][e][1] + red_c[2][e][1] + red_c[3][e][1] + bc2[1];
      vc = red_c[0][e][2] + red_c[1][e][2] + red_c[2][e][2] + red_c[3][e][2] + bc2[2];
    }
    const float pfc = pf * gt;
    const int bm = b * cM + m;
    gt_w[bm] = gt; wvp_w[bm] = vp; wvc_w[bm] = vc; pfc_w[bm] = pfc;
    out[b * ZROW + m] = pfc;
    out[b * ZROW + cM + cN + m] = gt;
  }
}

// ---------------- v einsums ----------------
__global__ __launch_bounds__(256) void k_v(const float* __restrict__ incP, const float* __restrict__ incC,
                                           const float* __restrict__ wvp, const float* __restrict__ wvc,
                                           const float* __restrict__ invdeg, float* __restrict__ v_w,
                                           float* __restrict__ out) {
  const int wid = blockIdx.x * 4 + (threadIdx.x >> 6);
  const int lane = threadIdx.x & 63;
  const int b = wid / cN, n = wid % cN;
  const size_t rowoff = (size_t)(b * cN + n) * cM + lane * 8;
  const float4 p0 = *(const float4*)(incP + rowoff);
  const float4 p1 = *(const float4*)(incP + rowoff + 4);
  const float4 c0 = *(const float4*)(incC + rowoff);
  const float4 c1 = *(const float4*)(incC + rowoff + 4);
  const float* wp = wvp + b * cM + lane * 8;
  const float* wc = wvc + b * cM + lane * 8;
  float s;
  s = p0.x * wp[0] + p0.y * wp[1] + p0.z * wp[2] + p0.w * wp[3] +
      p1.x * wp[4] + p1.y * wp[5] + p1.z * wp[6] + p1.w * wp[7];
  s += c0.x * wc[0] + c0.y * wc[1] + c0.z * wc[2] + c0.w * wc[3] +
       c1.x * wc[4] + c1.y * wc[5] + c1.z * wc[6] + c1.w * wc[7];
#pragma unroll
  for (int off = 32; off >= 1; off >>= 1) s += __shfl_down(s, off);
  if (lane == 0) {
    float val = invdeg[b * cN + n] * s;
    if (n == 0) val = 1.0f;
    v_w[b * cN + n] = val;
    out[b * ZROW + cM + n] = val;
  }
}

// ---------------- q_fc = (A^T v) * graph_topo ----------------
__global__ __launch_bounds__(256) void k_qfc(const float* __restrict__ A, const float* __restrict__ v_w,
                                             const float* __restrict__ gt_w, float* __restrict__ qfc_w,
                                             float* __restrict__ out) {
  __shared__ float vs[cN];
  const int b = blockIdx.x >> 1;
  const int m = ((blockIdx.x & 1) << 8) + threadIdx.x;
  for (int i = threadIdx.x; i < cN; i += 256) vs[i] = v_w[b * cN + i];
  __syncthreads();
  float s = 0.f;
  for (int n = 0; n < cN; ++n) s = fmaf(A[n * cM + m], vs[n], s);
  const int bm = b * cM + m;
  const float q = s * gt_w[bm];
  qfc_w[bm] = q;
  out[ZBASE + b * CROW + m] = q;
}

// ---------------- pg / qg: one wave per (b,n); coalesced A-row reads ----------------
__global__ __launch_bounds__(256) void k_pgqg(const float* __restrict__ A, const float* __restrict__ x,
                                              const float* __restrict__ pfc, const float* __restrict__ qfc,
                                              float* __restrict__ out) {
  const int wid = blockIdx.x * 4 + (threadIdx.x >> 6);
  const int lane = threadIdx.x & 63;
  const int b = wid / cN, n = wid - b * cN;
  const float* ar = A + (size_t)n * cM + lane * 8;
  const float* pf = pfc + b * cM + lane * 8;
  const float* qf = qfc + b * cM + lane * 8;
  const float4 a0 = *(const float4*)(ar);
  const float4 a1 = *(const float4*)(ar + 4);
  float ps, qs;
  ps = a0.x * pf[0] + a0.y * pf[1] + a0.z * pf[2] + a0.w * pf[3] +
       a1.x * pf[4] + a1.y * pf[5] + a1.z * pf[6] + a1.w * pf[7];
  qs = a0.x * qf[0] + a0.y * qf[1] + a0.z * qf[2] + a0.w * qf[3] +
       a1.x * qf[4] + a1.y * qf[5] + a1.z * qf[6] + a1.w * qf[7];
#pragma unroll
  for (int off = 32; off >= 1; off >>= 1) {
    ps += __shfl_down(ps, off);
    qs += __shfl_down(qs, off);
  }
  if (lane == 0) {
    out[ZBASE + b * CROW + cM + n] = x[2 * (size_t)wid] + ps;
    out[ZBASE + b * CROW + cM + cN + n] = x[2 * (size_t)wid + 1] + qs;
  }
}

extern "C" void kernel_launch(void* const* d_in, const int* in_sizes, int n_in,
                              void* d_out, int out_size, void* d_ws, size_t ws_size,
                              hipStream_t stream) {
  const bool dict_order = (in_sizes[1] == 2 * cE);
  int IEI, INSW, IIVD, IIP, IIC, IA, IW;
  if (dict_order) { IEI = 1; INSW = 2; IIVD = 3; IIP = 4; IIC = 5; IA = 6; IW = 7; }
  else            { IIVD = 1; IIP = 2; IIC = 3; IA = 4; IW = 5; IEI = 17; INSW = 18; }

  const float* x = (const float*)d_in[0];
  const int* ei_raw = (const int*)d_in[IEI];
  const int* nsw_raw = (const int*)d_in[INSW];
  const float* invdeg = (const float*)d_in[IIVD];
  const float* incP = (const float*)d_in[IIP];
  const float* incC = (const float*)d_in[IIC];
  const float* A = (const float*)d_in[IA];
  const float* W1 = (const float*)d_in[IW + 0];
  const float* b1 = (const float*)d_in[IW + 1];
  const float* W2 = (const float*)d_in[IW + 2];
  const float* b2 = (const float*)d_in[IW + 3];
  const float* Ws1 = (const float*)d_in[IW + 4];
  const float* bs1 = (const float*)d_in[IW + 5];
  const float* Ws2 = (const float*)d_in[IW + 6];
  const float* bs2 = (const float*)d_in[IW + 7];
  const float* Wc1 = (const float*)d_in[IW + 8];
  const float* bc1 = (const float*)d_in[IW + 9];
  const float* Wc2 = (const float*)d_in[IW + 10];
  const float* bc2 = (const float*)d_in[IW + 11];
  float* out = (float*)d_out;

  // ---- workspace (~48 MB; well under proven 83.6 MB) ----
  char* w = (char*)d_ws;
  auto alloc = [&](size_t bytes) { void* p = (void*)w; w += (bytes + 255) & ~(size_t)255; return p; };
  float* dinv = (float*)alloc((size_t)cNN * 4);
  int* ei = (int*)alloc((size_t)2 * cE * 4);
  int* nsw = (int*)alloc((size_t)cB * 4);
  bf16* hbufA = (bf16*)alloc((size_t)cNN * cH * 2);  // h2raw
  bf16* hbufB = (bf16*)alloc((size_t)cNN * cH * 2);  // h1 -> xg
  int* csr_off = (int*)alloc((size_t)cB * (cN + 1) * 4);
  int* csr_src = (int*)alloc((size_t)cE * 4);
  float* csr_nrm = (float*)alloc((size_t)cE * 4);
  float* a0_w = (float*)alloc((size_t)cNN * 4);
  float* a1_w = (float*)alloc((size_t)cNN * 4);
  float* aw_w = (float*)alloc((size_t)cNN * 4);
  bf16* Ws1t = (bf16*)alloc((size_t)512 * 256 * 2);
  bf16* Wc1t = (bf16*)alloc((size_t)384 * 256 * 2);
  bf16* W2t = (bf16*)alloc((size_t)128 * 128 * 2);
  float* g_s = (float*)alloc((size_t)cB * 512 * 4);
  float* g_c = (float*)alloc((size_t)cB * 384 * 4);
  float* Wc2p = (float*)alloc((size_t)384 * 4 * 4);
  float* gt_w = (float*)alloc((size_t)cB * cM * 4);
  float* wvp_w = (float*)alloc((size_t)cB * cM * 4);
  float* wvc_w = (float*)alloc((size_t)cB * cM * 4);
  float* pfc_w = (float*)alloc((size_t)cB * cM * 4);
  float* qfc_w = (float*)alloc((size_t)cB * cM * 4);
  float* v_w = (float*)alloc((size_t)cB * cN * 4);

  const int NH = cNN * cH;
  k_norm_idx<<<(2 * cE) / 256, 256, 0, stream>>>(ei_raw, nsw_raw, ei, nsw);
  k_csr2<<<cB, 512, 0, stream>>>(ei, dinv, csr_off, csr_src, csr_nrm);

  // GCN layer 1 (analytic rank-3): 3-scalar gather + elementwise expansion -> h1 in hbufB
  k_gath3<<<cB, 384, 0, stream>>>(csr_off, csr_src, csr_nrm, x, dinv, a0_w, a1_w, aw_w);
  k_h1a<<<NH / 256, 256, 0, stream>>>(a0_w, a1_w, aw_w, W1, b1, hbufB);

  // weight prep (no deps on h)
  k_wt<<<512, 256, 0, stream>>>(Ws1, Wc1, Wc2, W2, Ws1t, Wc1t, Wc2p, W2t);

  // GCN layer 2: lin2 B -> A (h2raw) on MFMA; gather A -> B (xg)
  k_lin2_mfma<<<cNN / 64, 256, 0, stream>>>(hbufB, W2t, b2, hbufA);
  k_gather<<<cNN / 4, 256, 0, stream>>>(csr_off, csr_src, csr_nrm, hbufA, dinv, hbufB);

  bf16* xg = hbufB;
  k_xgg<<<cB, 512, 0, stream>>>(xg, Ws1, bs1, Wc1, bc1, g_s, g_c);

  // per-edge MLPs on matrix cores (mask-skip + XCD-local batch tiles)
  k_mlp_mfma<<<cB * 8, 256, 0, stream>>>(ei, nsw, xg, Ws1t, Wc1t, g_s, g_c,
                                         Ws2, bs2, Wc2p, bc2,
                                         gt_w, wvp_w, wvc_w, pfc_w, out);

  k_v<<<cB * cN / 4, 256, 0, stream>>>(incP, incC, wvp_w, wvc_w, invdeg, v_w, out);
  k_qfc<<<cB * cM / 256, 256, 0, stream>>>(A, v_w, gt_w, qfc_w, out);
  k_pgqg<<<cNN / 4, 256, 0, stream>>>(A, x, pfc_w, qfc_w, out);
}